// Round 1
// baseline (1850.630 us; speedup 1.0000x reference)
//
#include <hip/hip_runtime.h>
#include <math.h>

// Problem constants
#define FL 41            // filter length
#define NH 32            // hidden channels
// ws float offsets
#define WS_E0  0         // encode filter region0 [32][41]
#define WS_E1  1312
#define WS_G0  2624      // decode filter region0
#define WS_G1  3936
#define WS_W2T 5248      // normalized W2^T [32][256]

// ---------------------------------------------------------------- setup ----
__global__ __launch_bounds__(256) void setup_kernel(
    const float* __restrict__ V2, const float* __restrict__ mus,
    const float* __restrict__ sigmas, const float* __restrict__ scaling,
    float* __restrict__ ws)
{
    const int tid = threadIdx.x;
    __shared__ float nrm[NH];
    if (tid < NH) {
        float s = 0.f;
        for (int j = 0; j < 256; ++j) { float v = V2[j*NH + tid]; s += v*v; }
        nrm[tid] = sqrtf(s);
    }
    __syncthreads();
    // W2T[h][j] = V2[j][h] / nrm[h]
    for (int idx = tid; idx < NH*256; idx += 256) {
        int h = idx >> 8, j = idx & 255;
        ws[WS_W2T + idx] = V2[j*NH + h] / nrm[h];
    }
    // filters: order e0,e1,g0,g1 ; each [32][41]
    for (int idx = tid; idx < 4*NH*FL; idx += 256) {
        int bank = idx / (NH*FL);
        int rem  = idx - bank*(NH*FL);
        int h = rem / FL, l = rem - h*FL;
        int r = bank & 1;
        float mu = mus[r*NH + h];
        float sg = fmaxf(sigmas[r*NH + h], 1.0f);  // clamp(min=1)
        float C  = scaling[r*NH + h];
        float m  = (bank < 2) ? -mu : mu;          // encode uses flipped mu
        float x  = (float)(l - 21);                // XVALS = -21..19
        float dd = (x - m) / sg;
        ws[idx] = C * expf(-0.5f * dd * dd);
    }
}

// ----------------------------------------------------------------- proj ----
// z0 = x0 @ W1[:, :128]^T ; z1 = x1 @ W1[:, 128:]^T      ([T,32] each)
// Block: 256 thr, 128 rows/block. LDS: X chunk transposed + W chunk.
__global__ __launch_bounds__(256) void proj_kernel(
    const float* __restrict__ x0, const float* __restrict__ x1,
    const float* __restrict__ W1,
    float* __restrict__ z0, float* __restrict__ z1, int T)
{
    __shared__ float xT[2][32][132];  // [region][c][s pad]
    __shared__ float wT[2][32][36];   // [region][c][h pad]
    const int tid  = threadIdx.x;
    const int row0 = blockIdx.x * 128;

    const int reg = tid >> 7;          // 0..1
    const int h0  = ((tid >> 5) & 3) * 8;
    const int m   = tid & 31;          // s0 = 4*m

    float acc[4][8];
#pragma unroll
    for (int i = 0; i < 4; ++i)
#pragma unroll
        for (int j = 0; j < 8; ++j) acc[i][j] = 0.f;

    for (int kc = 0; kc < 4; ++kc) {
        const int c0 = kc * 32;
        // stage X transposed: 8 lanes cover 128B contiguous per row
#pragma unroll
        for (int r = 0; r < 2; ++r) {
            const float* __restrict__ xp = r ? x1 : x0;
#pragma unroll
            for (int p = 0; p < 4; ++p) {
                const int row = p*32 + (tid >> 3);
                const int c   = (tid & 7) * 4;
                const float4 v = *reinterpret_cast<const float4*>(
                    &xp[(size_t)(row0 + row)*128 + c0 + c]);
                xT[r][c+0][row] = v.x; xT[r][c+1][row] = v.y;
                xT[r][c+2][row] = v.z; xT[r][c+3][row] = v.w;
            }
        }
        // stage W chunk (both halves), transposed
        {
            const int h = tid >> 3;
            const int c = (tid & 7) * 4;
            const float4 a = *reinterpret_cast<const float4*>(&W1[h*256 + c0 + c]);
            wT[0][c+0][h] = a.x; wT[0][c+1][h] = a.y;
            wT[0][c+2][h] = a.z; wT[0][c+3][h] = a.w;
            const float4 b = *reinterpret_cast<const float4*>(&W1[h*256 + 128 + c0 + c]);
            wT[1][c+0][h] = b.x; wT[1][c+1][h] = b.y;
            wT[1][c+2][h] = b.z; wT[1][c+3][h] = b.w;
        }
        __syncthreads();
#pragma unroll
        for (int c = 0; c < 32; ++c) {
            const float4 xv = *reinterpret_cast<const float4*>(&xT[reg][c][m*4]);
            const float4 wa = *reinterpret_cast<const float4*>(&wT[reg][c][h0]);
            const float4 wb = *reinterpret_cast<const float4*>(&wT[reg][c][h0+4]);
            const float xs[4] = {xv.x, xv.y, xv.z, xv.w};
            const float wv[8] = {wa.x, wa.y, wa.z, wa.w, wb.x, wb.y, wb.z, wb.w};
#pragma unroll
            for (int i = 0; i < 4; ++i)
#pragma unroll
                for (int j = 0; j < 8; ++j) acc[i][j] += xs[i] * wv[j];
        }
        __syncthreads();
    }
    float* __restrict__ zp = reg ? z1 : z0;
#pragma unroll
    for (int i = 0; i < 4; ++i) {
        const size_t r = (size_t)(row0 + m*4 + i) * NH + h0;
        float4 o0 = make_float4(acc[i][0], acc[i][1], acc[i][2], acc[i][3]);
        float4 o1 = make_float4(acc[i][4], acc[i][5], acc[i][6], acc[i][7]);
        *reinterpret_cast<float4*>(&zp[r])   = o0;
        *reinterpret_cast<float4*>(&zp[r+4]) = o1;
    }
}

// --------------------------------------------------------------- encode ----
// z[t,h] = sum_l z0[t+l,h]*e0[h,l] + z1[t+l,h]*e1[h,l] + b1[h]
__global__ __launch_bounds__(256) void encode_kernel(
    const float* __restrict__ z0, const float* __restrict__ z1,
    const float* __restrict__ b1, const float* __restrict__ ws,
    float* __restrict__ z, int T, int T1)
{
    __shared__ float s0[104][NH];
    __shared__ float s1[104][NH];
    const int tid = threadIdx.x;
    const int t0  = blockIdx.x * 64;
    for (int idx = tid; idx < 104*NH/4; idx += 256) {
        const int f = idx*4, row = f >> 5, col = f & 31;
        const int gr = t0 + row;
        if (gr < T) {
            *reinterpret_cast<float4*>(&s0[row][col]) =
                *reinterpret_cast<const float4*>(&z0[(size_t)gr*NH + col]);
            *reinterpret_cast<float4*>(&s1[row][col]) =
                *reinterpret_cast<const float4*>(&z1[(size_t)gr*NH + col]);
        }
    }
    __syncthreads();
    const int h = tid & 31;
    const int g = tid >> 5;           // 8 groups x 8 t
    float e0r[FL], e1r[FL];
#pragma unroll
    for (int l = 0; l < FL; ++l) {
        e0r[l] = ws[WS_E0 + h*FL + l];
        e1r[l] = ws[WS_E1 + h*FL + l];
    }
    float acc[8];
    const float bb = b1[h];
#pragma unroll
    for (int i = 0; i < 8; ++i) acc[i] = bb;
    const int tb = g * 8;
#pragma unroll
    for (int s = 0; s < 48; ++s) {
        const float a0 = s0[tb + s][h];
        const float a1 = s1[tb + s][h];
#pragma unroll
        for (int i = 0; i < 8; ++i) {
            const int l = s - i;
            if (l >= 0 && l < FL) acc[i] += a0*e0r[l] + a1*e1r[l];
        }
    }
#pragma unroll
    for (int i = 0; i < 8; ++i) {
        const int t = t0 + tb + i;
        if (t < T1) z[(size_t)t*NH + h] = acc[i];
    }
}

// --------------------------------------------------------------- decode ----
// zd_r[t,h] = sum_l z[t+l,h]*g_r[h,l]
__global__ __launch_bounds__(256) void decode_kernel(
    const float* __restrict__ z, const float* __restrict__ ws,
    float* __restrict__ zd0, float* __restrict__ zd1, int T1, int T2)
{
    __shared__ float sz[72][NH];
    const int tid = threadIdx.x;
    const int t0  = blockIdx.x * 32;
    for (int idx = tid; idx < 72*NH/4; idx += 256) {
        const int f = idx*4, row = f >> 5, col = f & 31;
        const int gr = t0 + row;
        if (gr < T1)
            *reinterpret_cast<float4*>(&sz[row][col]) =
                *reinterpret_cast<const float4*>(&z[(size_t)gr*NH + col]);
    }
    __syncthreads();
    const int h = tid & 31;
    const int r = (tid >> 5) & 1;
    const int g = tid >> 6;           // 4 groups x 8 t
    float fr[FL];
    const float* __restrict__ fb = ws + (r ? WS_G1 : WS_G0);
#pragma unroll
    for (int l = 0; l < FL; ++l) fr[l] = fb[h*FL + l];
    float acc[8];
#pragma unroll
    for (int i = 0; i < 8; ++i) acc[i] = 0.f;
    const int tb = g * 8;
#pragma unroll
    for (int s = 0; s < 48; ++s) {
        const float a = sz[tb + s][h];
#pragma unroll
        for (int i = 0; i < 8; ++i) {
            const int l = s - i;
            if (l >= 0 && l < FL) acc[i] += a * fr[l];
        }
    }
    float* __restrict__ zd = r ? zd1 : zd0;
#pragma unroll
    for (int i = 0; i < 8; ++i) {
        const int t = t0 + tb + i;
        if (t < T2) zd[(size_t)t*NH + h] = acc[i];
    }
}

// -------------------------------------------------------------- readout ----
// xh0 = zd0 @ W2T[:, :128] + b2[:128] ; xh1 = zd1 @ W2T[:, 128:] + b2[128:]
__global__ __launch_bounds__(256) void readout_kernel(
    const float* __restrict__ zd0, const float* __restrict__ zd1,
    const float* __restrict__ W2T, const float* __restrict__ b2,
    float* __restrict__ xh0, float* __restrict__ xh1, int T2)
{
    __shared__ float zT[2][NH][68];   // [region][h][t-local pad]
    __shared__ float w2[NH][264];     // W2T padded
    const int tid = threadIdx.x;
    const int t0  = blockIdx.x * 64;
    // stage W2T (hot in L2/L3 across blocks)
    for (int idx = tid; idx < NH*256/4; idx += 256) {
        const int f = idx*4, h = f >> 8, j = f & 255;
        *reinterpret_cast<float4*>(&w2[h][j]) =
            *reinterpret_cast<const float4*>(&W2T[h*256 + j]);
    }
    // stage zd transposed
    for (int idx = tid; idx < 64*NH/4; idx += 256) {
        const int tl = idx >> 3, hh = (idx & 7) * 4;
        const int t  = t0 + tl;
        float4 a = make_float4(0.f,0.f,0.f,0.f), b = make_float4(0.f,0.f,0.f,0.f);
        if (t < T2) {
            a = *reinterpret_cast<const float4*>(&zd0[(size_t)t*NH + hh]);
            b = *reinterpret_cast<const float4*>(&zd1[(size_t)t*NH + hh]);
        }
        zT[0][hh+0][tl] = a.x; zT[0][hh+1][tl] = a.y;
        zT[0][hh+2][tl] = a.z; zT[0][hh+3][tl] = a.w;
        zT[1][hh+0][tl] = b.x; zT[1][hh+1][tl] = b.y;
        zT[1][hh+2][tl] = b.z; zT[1][hh+3][tl] = b.w;
    }
    __syncthreads();
    const int m  = tid & 15;          // t = 4m..4m+3
    const int jq = tid >> 4;          // 16 groups of 16 j
    const int rg = jq >> 3;           // region
    const int j0 = jq * 16;           // global j 0..255
    float acc[4][16];
    float bv[16];
#pragma unroll
    for (int j = 0; j < 16; ++j) bv[j] = b2[j0 + j];
#pragma unroll
    for (int i = 0; i < 4; ++i)
#pragma unroll
        for (int j = 0; j < 16; ++j) acc[i][j] = bv[j];
#pragma unroll
    for (int h = 0; h < NH; ++h) {
        const float4 zv = *reinterpret_cast<const float4*>(&zT[rg][h][m*4]);
        const float zz[4] = {zv.x, zv.y, zv.z, zv.w};
        float wv[16];
#pragma unroll
        for (int k = 0; k < 4; ++k) {
            const float4 w4 = *reinterpret_cast<const float4*>(&w2[h][j0 + 4*k]);
            wv[4*k+0] = w4.x; wv[4*k+1] = w4.y; wv[4*k+2] = w4.z; wv[4*k+3] = w4.w;
        }
#pragma unroll
        for (int i = 0; i < 4; ++i)
#pragma unroll
            for (int j = 0; j < 16; ++j) acc[i][j] += zz[i] * wv[j];
    }
    float* __restrict__ xp = rg ? xh1 : xh0;
    const int jl = j0 & 127;
#pragma unroll
    for (int i = 0; i < 4; ++i) {
        const int t = t0 + 4*m + i;
        if (t < T2) {
#pragma unroll
            for (int k = 0; k < 4; ++k) {
                float4 o = make_float4(acc[i][4*k+0], acc[i][4*k+1],
                                       acc[i][4*k+2], acc[i][4*k+3]);
                *reinterpret_cast<float4*>(&xp[(size_t)t*128 + jl + 4*k]) = o;
            }
        }
    }
}

// ---------------------------------------------------------------- launch ---
extern "C" void kernel_launch(void* const* d_in, const int* in_sizes, int n_in,
                              void* d_out, int out_size, void* d_ws, size_t ws_size,
                              hipStream_t stream)
{
    const float* x0      = (const float*)d_in[0];
    const float* x1      = (const float*)d_in[1];
    const float* W1      = (const float*)d_in[2];
    const float* b1      = (const float*)d_in[3];
    const float* V2      = (const float*)d_in[4];
    const float* b2      = (const float*)d_in[5];
    const float* mus     = (const float*)d_in[6];
    const float* sigmas  = (const float*)d_in[7];
    const float* scaling = (const float*)d_in[8];
    float* out = (float*)d_out;
    float* ws  = (float*)d_ws;

    const int T  = in_sizes[0] / 128;
    const int T1 = T - 40;
    const int T2 = T - 80;

    // output regions
    float* zd0 = out;
    float* zd1 = out + (size_t)T2 * NH;
    float* xh0 = out + (size_t)2 * T2 * NH;
    float* xh1 = xh0 + (size_t)T2 * 128;

    // intermediates placed inside not-yet-written output regions:
    //   z0,z1 (T*32 each = 16.8M floats total) fit in xh0 region (T2*128 = 33.5M)
    //   z (T1*32) fits in xh1 region; all dead before their region is written.
    float* z0 = xh0;
    float* z1 = xh0 + (size_t)T * NH;
    float* z  = xh1;

    setup_kernel<<<1, 256, 0, stream>>>(V2, mus, sigmas, scaling, ws);
    proj_kernel<<<T / 128, 256, 0, stream>>>(x0, x1, W1, z0, z1, T);
    encode_kernel<<<(T1 + 63) / 64, 256, 0, stream>>>(z0, z1, b1, ws, z, T, T1);
    decode_kernel<<<(T2 + 31) / 32, 256, 0, stream>>>(z, ws, zd0, zd1, T1, T2);
    readout_kernel<<<(T2 + 63) / 64, 256, 0, stream>>>(zd0, zd1, ws + WS_W2T, b2,
                                                       xh0, xh1, T2);
}

// Round 3
// 674.849 us; speedup vs baseline: 2.7423x; 2.7423x over previous
//
#include <hip/hip_runtime.h>
#include <math.h>

// Problem constants
#define FL 41            // filter length
#define NH 32            // hidden channels
// ws float offsets
#define WS_E0  0         // encode filter region0 [32][41]
#define WS_E1  1312
#define WS_G0  2624      // decode filter region0
#define WS_G1  3936
#define WS_W2T 5248      // normalized W2^T [32][256]

// ---------------------------------------------------------------- setup ----
__global__ __launch_bounds__(256) void setup_kernel(
    const float* __restrict__ V2, const float* __restrict__ mus,
    const float* __restrict__ sigmas, const float* __restrict__ scaling,
    float* __restrict__ ws)
{
    const int tid = threadIdx.x;
    __shared__ float nrm[NH];
    // parallel column-norm: 8 threads per h, each sums 32 strided rows
    {
        const int h = tid >> 3;          // 0..31
        const int s = tid & 7;           // 0..7
        float p = 0.f;
        for (int jj = 0; jj < 32; ++jj) {
            const float v = V2[(s + jj*8)*NH + h];
            p += v*v;
        }
        p += __shfl_xor(p, 1, 8);
        p += __shfl_xor(p, 2, 8);
        p += __shfl_xor(p, 4, 8);
        if (s == 0) nrm[h] = sqrtf(p);
    }
    __syncthreads();
    // W2T[h][j] = V2[j][h] / nrm[h]
    for (int idx = tid; idx < NH*256; idx += 256) {
        int h = idx >> 8, j = idx & 255;
        ws[WS_W2T + idx] = V2[j*NH + h] / nrm[h];
    }
    // filters: order e0,e1,g0,g1 ; each [32][41]
    for (int idx = tid; idx < 4*NH*FL; idx += 256) {
        int bank = idx / (NH*FL);
        int rem  = idx - bank*(NH*FL);
        int h = rem / FL, l = rem - h*FL;
        int r = bank & 1;
        float mu = mus[r*NH + h];
        float sg = fmaxf(sigmas[r*NH + h], 1.0f);  // clamp(min=1)
        float C  = scaling[r*NH + h];
        float m  = (bank < 2) ? -mu : mu;          // encode uses flipped mu
        float x  = (float)(l - 21);                // XVALS = -21..19
        float dd = (x - m) / sg;
        ws[idx] = C * expf(-0.5f * dd * dd);
    }
}

// ----------------------------------------------------------------- proj ----
// z0 = x0 @ W1[:, :128]^T ; z1 = x1 @ W1[:, 128:]^T      ([T,32] each)
__global__ __launch_bounds__(256) void proj_kernel(
    const float* __restrict__ x0, const float* __restrict__ x1,
    const float* __restrict__ W1,
    float* __restrict__ z0, float* __restrict__ z1, int T)
{
    __shared__ float xT[2][32][132];  // [region][c][s pad]
    __shared__ float wT[2][32][36];   // [region][c][h pad]
    const int tid  = threadIdx.x;
    const int row0 = blockIdx.x * 128;

    const int reg = tid >> 7;          // 0..1
    const int h0  = ((tid >> 5) & 3) * 8;
    const int m   = tid & 31;          // s0 = 4*m

    float acc[4][8];
#pragma unroll
    for (int i = 0; i < 4; ++i)
#pragma unroll
        for (int j = 0; j < 8; ++j) acc[i][j] = 0.f;

    for (int kc = 0; kc < 4; ++kc) {
        const int c0 = kc * 32;
#pragma unroll
        for (int r = 0; r < 2; ++r) {
            const float* __restrict__ xp = r ? x1 : x0;
#pragma unroll
            for (int p = 0; p < 4; ++p) {
                const int row = p*32 + (tid >> 3);
                const int c   = (tid & 7) * 4;
                const float4 v = *reinterpret_cast<const float4*>(
                    &xp[(size_t)(row0 + row)*128 + c0 + c]);
                xT[r][c+0][row] = v.x; xT[r][c+1][row] = v.y;
                xT[r][c+2][row] = v.z; xT[r][c+3][row] = v.w;
            }
        }
        {
            const int h = tid >> 3;
            const int c = (tid & 7) * 4;
            const float4 a = *reinterpret_cast<const float4*>(&W1[h*256 + c0 + c]);
            wT[0][c+0][h] = a.x; wT[0][c+1][h] = a.y;
            wT[0][c+2][h] = a.z; wT[0][c+3][h] = a.w;
            const float4 b = *reinterpret_cast<const float4*>(&W1[h*256 + 128 + c0 + c]);
            wT[1][c+0][h] = b.x; wT[1][c+1][h] = b.y;
            wT[1][c+2][h] = b.z; wT[1][c+3][h] = b.w;
        }
        __syncthreads();
#pragma unroll
        for (int c = 0; c < 32; ++c) {
            const float4 xv = *reinterpret_cast<const float4*>(&xT[reg][c][m*4]);
            const float4 wa = *reinterpret_cast<const float4*>(&wT[reg][c][h0]);
            const float4 wb = *reinterpret_cast<const float4*>(&wT[reg][c][h0+4]);
            const float xs[4] = {xv.x, xv.y, xv.z, xv.w};
            const float wv[8] = {wa.x, wa.y, wa.z, wa.w, wb.x, wb.y, wb.z, wb.w};
#pragma unroll
            for (int i = 0; i < 4; ++i)
#pragma unroll
                for (int j = 0; j < 8; ++j) acc[i][j] += xs[i] * wv[j];
        }
        __syncthreads();
    }
    float* __restrict__ zp = reg ? z1 : z0;
#pragma unroll
    for (int i = 0; i < 4; ++i) {
        const size_t r = (size_t)(row0 + m*4 + i) * NH + h0;
        float4 o0 = make_float4(acc[i][0], acc[i][1], acc[i][2], acc[i][3]);
        float4 o1 = make_float4(acc[i][4], acc[i][5], acc[i][6], acc[i][7]);
        *reinterpret_cast<float4*>(&zp[r])   = o0;
        *reinterpret_cast<float4*>(&zp[r+4]) = o1;
    }
}

// --------------------------------------------------------------- encode ----
__global__ __launch_bounds__(256) void encode_kernel(
    const float* __restrict__ z0, const float* __restrict__ z1,
    const float* __restrict__ b1, const float* __restrict__ ws,
    float* __restrict__ z, int T, int T1)
{
    __shared__ float s0[104][NH];
    __shared__ float s1[104][NH];
    const int tid = threadIdx.x;
    const int t0  = blockIdx.x * 64;
    for (int idx = tid; idx < 104*NH/4; idx += 256) {
        const int f = idx*4, row = f >> 5, col = f & 31;
        const int gr = t0 + row;
        if (gr < T) {
            *reinterpret_cast<float4*>(&s0[row][col]) =
                *reinterpret_cast<const float4*>(&z0[(size_t)gr*NH + col]);
            *reinterpret_cast<float4*>(&s1[row][col]) =
                *reinterpret_cast<const float4*>(&z1[(size_t)gr*NH + col]);
        }
    }
    __syncthreads();
    const int h = tid & 31;
    const int g = tid >> 5;           // 8 groups x 8 t
    float e0r[FL], e1r[FL];
#pragma unroll
    for (int l = 0; l < FL; ++l) {
        e0r[l] = ws[WS_E0 + h*FL + l];
        e1r[l] = ws[WS_E1 + h*FL + l];
    }
    float acc[8];
    const float bb = b1[h];
#pragma unroll
    for (int i = 0; i < 8; ++i) acc[i] = bb;
    const int tb = g * 8;
#pragma unroll
    for (int s = 0; s < 48; ++s) {
        const float a0 = s0[tb + s][h];
        const float a1 = s1[tb + s][h];
#pragma unroll
        for (int i = 0; i < 8; ++i) {
            const int l = s - i;
            if (l >= 0 && l < FL) acc[i] += a0*e0r[l] + a1*e1r[l];
        }
    }
#pragma unroll
    for (int i = 0; i < 8; ++i) {
        const int t = t0 + tb + i;
        if (t < T1) z[(size_t)t*NH + h] = acc[i];
    }
}

// --------------------------------------------------------------- decode ----
__global__ __launch_bounds__(256) void decode_kernel(
    const float* __restrict__ z, const float* __restrict__ ws,
    float* __restrict__ zd0, float* __restrict__ zd1, int T1, int T2)
{
    __shared__ float sz[72][NH];
    const int tid = threadIdx.x;
    const int t0  = blockIdx.x * 32;
    for (int idx = tid; idx < 72*NH/4; idx += 256) {
        const int f = idx*4, row = f >> 5, col = f & 31;
        const int gr = t0 + row;
        if (gr < T1)
            *reinterpret_cast<float4*>(&sz[row][col]) =
                *reinterpret_cast<const float4*>(&z[(size_t)gr*NH + col]);
    }
    __syncthreads();
    const int h = tid & 31;
    const int r = (tid >> 5) & 1;
    const int g = tid >> 6;           // 4 groups x 8 t
    float fr[FL];
    const float* __restrict__ fb = ws + (r ? WS_G1 : WS_G0);
#pragma unroll
    for (int l = 0; l < FL; ++l) fr[l] = fb[h*FL + l];
    float acc[8];
#pragma unroll
    for (int i = 0; i < 8; ++i) acc[i] = 0.f;
    const int tb = g * 8;
#pragma unroll
    for (int s = 0; s < 48; ++s) {
        const float a = sz[tb + s][h];
#pragma unroll
        for (int i = 0; i < 8; ++i) {
            const int l = s - i;
            if (l >= 0 && l < FL) acc[i] += a * fr[l];
        }
    }
    float* __restrict__ zd = r ? zd1 : zd0;
#pragma unroll
    for (int i = 0; i < 8; ++i) {
        const int t = t0 + tb + i;
        if (t < T2) zd[(size_t)t*NH + h] = acc[i];
    }
}

// -------------------------------------------------------------- readout ----
// xh0 = zd0 @ W2T[:, :128] + b2[:128] ; xh1 = zd1 @ W2T[:, 128:] + b2[128:]
// Block: 256 thr, 32 t-rows, all 256 output cols.
// Thread (m = tid&15, jq = tid>>4): rows t0+2m, t0+2m+1; cols jq*4+64k+c
//   (k=0..3, c=0..3). Per k, the 16 jq-lanes read CONSECUTIVE float4s of
//   w2[h][...] -> 64 consecutive floats -> all 32 banks, conflict-free.
//   zT reads are 4-way wave-broadcast. acc[2][16] = 32 regs, no spill.
__global__ __launch_bounds__(256) void readout_kernel(
    const float* __restrict__ zd0, const float* __restrict__ zd1,
    const float* __restrict__ W2T, const float* __restrict__ b2,
    float* __restrict__ xh0, float* __restrict__ xh1, int T2)
{
    __shared__ float w2[NH][260];     // stride 260: 16B-aligned rows (65*16B)
    __shared__ float zT[2][NH][34];   // [region][h][t-local], even stride
    const int tid = threadIdx.x;
    const int t0  = blockIdx.x * 32;

    // stage W2T (L2-hot across blocks)
    for (int idx = tid; idx < NH*256/4; idx += 256) {
        const int f = idx*4, h = f >> 8, j = f & 255;
        *reinterpret_cast<float4*>(&w2[h][j]) =
            *reinterpret_cast<const float4*>(&W2T[h*256 + j]);
    }
    // stage zd transposed: 512 float4s
    for (int idx = tid; idx < 512; idx += 256) {
        const int r   = idx >> 8;
        const int rem = idx & 255;
        const int tl  = rem >> 3;          // 0..31
        const int hh  = (rem & 7) * 4;     // 0..28
        const int t   = t0 + tl;
        float4 v = make_float4(0.f, 0.f, 0.f, 0.f);
        if (t < T2) {
            const float* __restrict__ zp = r ? zd1 : zd0;
            v = *reinterpret_cast<const float4*>(&zp[(size_t)t*NH + hh]);
        }
        zT[r][hh+0][tl] = v.x; zT[r][hh+1][tl] = v.y;
        zT[r][hh+2][tl] = v.z; zT[r][hh+3][tl] = v.w;
    }
    __syncthreads();

    const int m  = tid & 15;          // t-pair index
    const int jq = tid >> 4;          // 0..15
    const int jb = jq * 4;

    float acc[2][16];
#pragma unroll
    for (int k = 0; k < 4; ++k)
#pragma unroll
        for (int c = 0; c < 4; ++c) {
            const float bv = b2[jb + 64*k + c];
            acc[0][4*k+c] = bv;
            acc[1][4*k+c] = bv;
        }

#pragma unroll 4
    for (int h = 0; h < NH; ++h) {
        const float2 za = *reinterpret_cast<const float2*>(&zT[0][h][m*2]);
        const float2 zb = *reinterpret_cast<const float2*>(&zT[1][h][m*2]);
        const float4 w0 = *reinterpret_cast<const float4*>(&w2[h][jb]);
        const float4 w1 = *reinterpret_cast<const float4*>(&w2[h][jb + 64]);
        const float4 w2v= *reinterpret_cast<const float4*>(&w2[h][jb + 128]);
        const float4 w3 = *reinterpret_cast<const float4*>(&w2[h][jb + 192]);
        acc[0][0]  += za.x*w0.x; acc[0][1]  += za.x*w0.y;
        acc[0][2]  += za.x*w0.z; acc[0][3]  += za.x*w0.w;
        acc[0][4]  += za.x*w1.x; acc[0][5]  += za.x*w1.y;
        acc[0][6]  += za.x*w1.z; acc[0][7]  += za.x*w1.w;
        acc[0][8]  += zb.x*w2v.x; acc[0][9]  += zb.x*w2v.y;
        acc[0][10] += zb.x*w2v.z; acc[0][11] += zb.x*w2v.w;
        acc[0][12] += zb.x*w3.x; acc[0][13] += zb.x*w3.y;
        acc[0][14] += zb.x*w3.z; acc[0][15] += zb.x*w3.w;
        acc[1][0]  += za.y*w0.x; acc[1][1]  += za.y*w0.y;
        acc[1][2]  += za.y*w0.z; acc[1][3]  += za.y*w0.w;
        acc[1][4]  += za.y*w1.x; acc[1][5]  += za.y*w1.y;
        acc[1][6]  += za.y*w1.z; acc[1][7]  += za.y*w1.w;
        acc[1][8]  += zb.y*w2v.x; acc[1][9]  += zb.y*w2v.y;
        acc[1][10] += zb.y*w2v.z; acc[1][11] += zb.y*w2v.w;
        acc[1][12] += zb.y*w3.x; acc[1][13] += zb.y*w3.y;
        acc[1][14] += zb.y*w3.z; acc[1][15] += zb.y*w3.w;
    }

#pragma unroll
    for (int i = 0; i < 2; ++i) {
        const int t = t0 + m*2 + i;
        if (t < T2) {
#pragma unroll
            for (int k = 0; k < 4; ++k) {
                float* __restrict__ xp = (k < 2) ? xh0 : xh1;
                const int jl = jb + 64 * (k & 1);
                float4 o = make_float4(acc[i][4*k+0], acc[i][4*k+1],
                                       acc[i][4*k+2], acc[i][4*k+3]);
                *reinterpret_cast<float4*>(&xp[(size_t)t*128 + jl]) = o;
            }
        }
    }
}

// ---------------------------------------------------------------- launch ---
extern "C" void kernel_launch(void* const* d_in, const int* in_sizes, int n_in,
                              void* d_out, int out_size, void* d_ws, size_t ws_size,
                              hipStream_t stream)
{
    const float* x0      = (const float*)d_in[0];
    const float* x1      = (const float*)d_in[1];
    const float* W1      = (const float*)d_in[2];
    const float* b1      = (const float*)d_in[3];
    const float* V2      = (const float*)d_in[4];
    const float* b2      = (const float*)d_in[5];
    const float* mus     = (const float*)d_in[6];
    const float* sigmas  = (const float*)d_in[7];
    const float* scaling = (const float*)d_in[8];
    float* out = (float*)d_out;
    float* ws  = (float*)d_ws;

    const int T  = in_sizes[0] / 128;
    const int T1 = T - 40;
    const int T2 = T - 80;

    float* zd0 = out;
    float* zd1 = out + (size_t)T2 * NH;
    float* xh0 = out + (size_t)2 * T2 * NH;
    float* xh1 = xh0 + (size_t)T2 * 128;

    // intermediates inside not-yet-written output regions (dead before overwrite)
    float* z0 = xh0;
    float* z1 = xh0 + (size_t)T * NH;
    float* z  = xh1;

    setup_kernel<<<1, 256, 0, stream>>>(V2, mus, sigmas, scaling, ws);
    proj_kernel<<<T / 128, 256, 0, stream>>>(x0, x1, W1, z0, z1, T);
    encode_kernel<<<(T1 + 63) / 64, 256, 0, stream>>>(z0, z1, b1, ws, z, T, T1);
    decode_kernel<<<(T2 + 31) / 32, 256, 0, stream>>>(z, ws, zd0, zd1, T1, T2);
    readout_kernel<<<(T2 + 31) / 32, 256, 0, stream>>>(zd0, zd1, ws + WS_W2T, b2,
                                                       xh0, xh1, T2);
}

// Round 5
// 658.590 us; speedup vs baseline: 2.8100x; 1.0247x over previous
//
#include <hip/hip_runtime.h>
#include <math.h>

// Problem constants
#define FL 41            // filter length
#define NH 32            // hidden channels
// ws float offsets
#define WS_E0  0         // encode filter region0 [32][41]
#define WS_E1  1312
#define WS_G0  2624      // decode filter region0
#define WS_G1  3936
#define WS_W2T 5248      // normalized W2^T [32][256]

// ---------------------------------------------------------------- setup ----
__global__ __launch_bounds__(256) void setup_kernel(
    const float* __restrict__ V2, const float* __restrict__ mus,
    const float* __restrict__ sigmas, const float* __restrict__ scaling,
    float* __restrict__ ws)
{
    const int tid = threadIdx.x;
    __shared__ float nrm[NH];
    // parallel column-norm: 8 threads per h, each sums 32 strided rows
    {
        const int h = tid >> 3;          // 0..31
        const int s = tid & 7;           // 0..7
        float p = 0.f;
        for (int jj = 0; jj < 32; ++jj) {
            const float v = V2[(s + jj*8)*NH + h];
            p += v*v;
        }
        p += __shfl_xor(p, 1, 8);
        p += __shfl_xor(p, 2, 8);
        p += __shfl_xor(p, 4, 8);
        if (s == 0) nrm[h] = sqrtf(p);
    }
    __syncthreads();
    // W2T[h][j] = V2[j][h] / nrm[h]
    for (int idx = tid; idx < NH*256; idx += 256) {
        int h = idx >> 8, j = idx & 255;
        ws[WS_W2T + idx] = V2[j*NH + h] / nrm[h];
    }
    // filters: order e0,e1,g0,g1 ; each [32][41]
    for (int idx = tid; idx < 4*NH*FL; idx += 256) {
        int bank = idx / (NH*FL);
        int rem  = idx - bank*(NH*FL);
        int h = rem / FL, l = rem - h*FL;
        int r = bank & 1;
        float mu = mus[r*NH + h];
        float sg = fmaxf(sigmas[r*NH + h], 1.0f);  // clamp(min=1)
        float C  = scaling[r*NH + h];
        float m  = (bank < 2) ? -mu : mu;          // encode uses flipped mu
        float x  = (float)(l - 21);                // XVALS = -21..19
        float dd = (x - m) / sg;
        ws[idx] = C * expf(-0.5f * dd * dd);
    }
}

// ----------------------------------------------------------------- proj ----
// z0 = x0 @ W1[:, :128]^T ; z1 = x1 @ W1[:, 128:]^T      ([T,32] each)
// (UNCHANGED from round 3 for differential attribution)
__global__ __launch_bounds__(256) void proj_kernel(
    const float* __restrict__ x0, const float* __restrict__ x1,
    const float* __restrict__ W1,
    float* __restrict__ z0, float* __restrict__ z1, int T)
{
    __shared__ float xT[2][32][132];  // [region][c][s pad]
    __shared__ float wT[2][32][36];   // [region][c][h pad]
    const int tid  = threadIdx.x;
    const int row0 = blockIdx.x * 128;

    const int reg = tid >> 7;          // 0..1
    const int h0  = ((tid >> 5) & 3) * 8;
    const int m   = tid & 31;          // s0 = 4*m

    float acc[4][8];
#pragma unroll
    for (int i = 0; i < 4; ++i)
#pragma unroll
        for (int j = 0; j < 8; ++j) acc[i][j] = 0.f;

    for (int kc = 0; kc < 4; ++kc) {
        const int c0 = kc * 32;
#pragma unroll
        for (int r = 0; r < 2; ++r) {
            const float* __restrict__ xp = r ? x1 : x0;
#pragma unroll
            for (int p = 0; p < 4; ++p) {
                const int row = p*32 + (tid >> 3);
                const int c   = (tid & 7) * 4;
                const float4 v = *reinterpret_cast<const float4*>(
                    &xp[(size_t)(row0 + row)*128 + c0 + c]);
                xT[r][c+0][row] = v.x; xT[r][c+1][row] = v.y;
                xT[r][c+2][row] = v.z; xT[r][c+3][row] = v.w;
            }
        }
        {
            const int h = tid >> 3;
            const int c = (tid & 7) * 4;
            const float4 a = *reinterpret_cast<const float4*>(&W1[h*256 + c0 + c]);
            wT[0][c+0][h] = a.x; wT[0][c+1][h] = a.y;
            wT[0][c+2][h] = a.z; wT[0][c+3][h] = a.w;
            const float4 b = *reinterpret_cast<const float4*>(&W1[h*256 + 128 + c0 + c]);
            wT[1][c+0][h] = b.x; wT[1][c+1][h] = b.y;
            wT[1][c+2][h] = b.z; wT[1][c+3][h] = b.w;
        }
        __syncthreads();
#pragma unroll
        for (int c = 0; c < 32; ++c) {
            const float4 xv = *reinterpret_cast<const float4*>(&xT[reg][c][m*4]);
            const float4 wa = *reinterpret_cast<const float4*>(&wT[reg][c][h0]);
            const float4 wb = *reinterpret_cast<const float4*>(&wT[reg][c][h0+4]);
            const float xs[4] = {xv.x, xv.y, xv.z, xv.w};
            const float wv[8] = {wa.x, wa.y, wa.z, wa.w, wb.x, wb.y, wb.z, wb.w};
#pragma unroll
            for (int i = 0; i < 4; ++i)
#pragma unroll
                for (int j = 0; j < 8; ++j) acc[i][j] += xs[i] * wv[j];
        }
        __syncthreads();
    }
    float* __restrict__ zp = reg ? z1 : z0;
#pragma unroll
    for (int i = 0; i < 4; ++i) {
        const size_t r = (size_t)(row0 + m*4 + i) * NH + h0;
        float4 o0 = make_float4(acc[i][0], acc[i][1], acc[i][2], acc[i][3]);
        float4 o1 = make_float4(acc[i][4], acc[i][5], acc[i][6], acc[i][7]);
        *reinterpret_cast<float4*>(&zp[r])   = o0;
        *reinterpret_cast<float4*>(&zp[r+4]) = o1;
    }
}

// --------------------------------------------------------------- encdec ----
// Fused encode+decode: z never touches HBM.
//   z[t,h]  = sum_l z0[t+l,h]*e0[h,l] + z1[t+l,h]*e1[h,l] + b1[h]
//   zd_r[t,h] = sum_l z[t+l,h]*g_r[h,l]
// Block: 512 thr, BT=128 zd rows. Stage z0,z1 rows [t0, t0+216);
// encode 176 z rows (16 groups x 11) into LDS; decode 128 zd rows
// (2 regions x 8 groups x 16). Filters one region at a time (41 VGPR).
#define ED_BT 128
#define ED_RS 216   // staged z0/z1 rows (176 + 40)
#define ED_ZR 176   // z tile rows (16*11)
__global__ __launch_bounds__(512) void encdec_kernel(
    const float* __restrict__ z0, const float* __restrict__ z1,
    const float* __restrict__ b1, const float* __restrict__ ws,
    float* __restrict__ zd0, float* __restrict__ zd1,
    int T, int T2)
{
    __shared__ float s0[ED_RS][NH];
    __shared__ float s1[ED_RS][NH];
    __shared__ float zt[ED_ZR][NH];
    const int tid = threadIdx.x;
    const int t0  = blockIdx.x * ED_BT;

    // stage z0,z1 rows [t0, t0+216), coalesced float4
    for (int idx = tid; idx < ED_RS*NH/4; idx += 512) {
        const int f = idx*4, row = f >> 5, col = f & 31;
        const int gr = t0 + row;
        float4 a = make_float4(0.f,0.f,0.f,0.f);
        float4 b = make_float4(0.f,0.f,0.f,0.f);
        if (gr < T) {
            a = *reinterpret_cast<const float4*>(&z0[(size_t)gr*NH + col]);
            b = *reinterpret_cast<const float4*>(&z1[(size_t)gr*NH + col]);
        }
        *reinterpret_cast<float4*>(&s0[row][col]) = a;
        *reinterpret_cast<float4*>(&s1[row][col]) = b;
    }
    __syncthreads();

    const int h = tid & 31;
    // ---- encode phase: 16 groups x 11 z-rows
    {
        const int g  = tid >> 5;        // 0..15
        const int tb = g * 11;
        float acc[11];
        const float bb = b1[h];
#pragma unroll
        for (int i = 0; i < 11; ++i) acc[i] = bb;
        float fr[FL];
#pragma unroll
        for (int l = 0; l < FL; ++l) fr[l] = ws[WS_E0 + h*FL + l];
#pragma unroll
        for (int s = 0; s < 51; ++s) {
            const float a0 = s0[tb + s][h];
#pragma unroll
            for (int i = 0; i < 11; ++i) {
                const int l = s - i;
                if (l >= 0 && l < FL) acc[i] += a0 * fr[l];
            }
        }
#pragma unroll
        for (int l = 0; l < FL; ++l) fr[l] = ws[WS_E1 + h*FL + l];
#pragma unroll
        for (int s = 0; s < 51; ++s) {
            const float a1 = s1[tb + s][h];
#pragma unroll
            for (int i = 0; i < 11; ++i) {
                const int l = s - i;
                if (l >= 0 && l < FL) acc[i] += a1 * fr[l];
            }
        }
#pragma unroll
        for (int i = 0; i < 11; ++i) zt[tb + i][h] = acc[i];
    }
    __syncthreads();

    // ---- decode phase: 2 regions x 8 groups x 16 zd-rows
    {
        const int rr = (tid >> 5) & 1;
        const int g  = tid >> 6;        // 0..7
        const int tb = g * 16;
        float fr[FL];
        const float* __restrict__ fb = ws + (rr ? WS_G1 : WS_G0);
#pragma unroll
        for (int l = 0; l < FL; ++l) fr[l] = fb[h*FL + l];
        float acc[16];
#pragma unroll
        for (int i = 0; i < 16; ++i) acc[i] = 0.f;
#pragma unroll
        for (int s = 0; s < 56; ++s) {
            const float a = zt[tb + s][h];
#pragma unroll
            for (int i = 0; i < 16; ++i) {
                const int l = s - i;
                if (l >= 0 && l < FL) acc[i] += a * fr[l];
            }
        }
        float* __restrict__ zd = rr ? zd1 : zd0;
#pragma unroll
        for (int i = 0; i < 16; ++i) {
            const int t = t0 + tb + i;
            if (t < T2) zd[(size_t)t*NH + h] = acc[i];
        }
    }
}

// -------------------------------------------------------------- readout ----
// xh0 = zd0 @ W2T[:, :128] + b2[:128] ; xh1 = zd1 @ W2T[:, 128:] + b2[128:]
// Block: 512 thr, 64 t-rows. Thread (m = tid&31, jq = tid>>5):
//   rows t0+2m, t0+2m+1; cols jq*4 + 64k + c. Per k, jq-lanes read
//   consecutive float4s of w2 -> conflict-free; zT float2 reads 2-way.
__global__ __launch_bounds__(512) void readout_kernel(
    const float* __restrict__ zd0, const float* __restrict__ zd1,
    const float* __restrict__ W2T, const float* __restrict__ b2,
    float* __restrict__ xh0, float* __restrict__ xh1, int T2)
{
    __shared__ float w2[NH][260];     // stride 260: 16B-aligned rows
    __shared__ float zT[2][NH][66];   // [region][h][t-local], even stride
    const int tid = threadIdx.x;
    const int t0  = blockIdx.x * 64;

    // stage W2T (L2-hot across blocks): 2048 float4s
    for (int idx = tid; idx < 2048; idx += 512) {
        const int h = idx >> 6, j = (idx & 63) * 4;
        *reinterpret_cast<float4*>(&w2[h][j]) =
            *reinterpret_cast<const float4*>(&W2T[h*256 + j]);
    }
    // stage zd transposed: 1024 float4s
    for (int idx = tid; idx < 1024; idx += 512) {
        const int r   = idx >> 9;
        const int rem = idx & 511;
        const int tl  = rem >> 3;          // 0..63
        const int hh  = (rem & 7) * 4;     // 0..28
        const int t   = t0 + tl;
        float4 v = make_float4(0.f, 0.f, 0.f, 0.f);
        if (t < T2) {
            const float* __restrict__ zp = r ? zd1 : zd0;
            v = *reinterpret_cast<const float4*>(&zp[(size_t)t*NH + hh]);
        }
        zT[r][hh+0][tl] = v.x; zT[r][hh+1][tl] = v.y;
        zT[r][hh+2][tl] = v.z; zT[r][hh+3][tl] = v.w;
    }
    __syncthreads();

    const int m  = tid & 31;          // t-pair index (64 rows)
    const int jq = tid >> 5;          // 0..15
    const int jb = jq * 4;

    float acc[2][16];
#pragma unroll
    for (int k = 0; k < 4; ++k)
#pragma unroll
        for (int c = 0; c < 4; ++c) {
            const float bv = b2[jb + 64*k + c];
            acc[0][4*k+c] = bv;
            acc[1][4*k+c] = bv;
        }

#pragma unroll 4
    for (int h = 0; h < NH; ++h) {
        const float2 za = *reinterpret_cast<const float2*>(&zT[0][h][m*2]);
        const float2 zb = *reinterpret_cast<const float2*>(&zT[1][h][m*2]);
        const float4 w0 = *reinterpret_cast<const float4*>(&w2[h][jb]);
        const float4 w1 = *reinterpret_cast<const float4*>(&w2[h][jb + 64]);
        const float4 w2v= *reinterpret_cast<const float4*>(&w2[h][jb + 128]);
        const float4 w3 = *reinterpret_cast<const float4*>(&w2[h][jb + 192]);
        acc[0][0]  += za.x*w0.x; acc[0][1]  += za.x*w0.y;
        acc[0][2]  += za.x*w0.z; acc[0][3]  += za.x*w0.w;
        acc[0][4]  += za.x*w1.x; acc[0][5]  += za.x*w1.y;
        acc[0][6]  += za.x*w1.z; acc[0][7]  += za.x*w1.w;
        acc[0][8]  += zb.x*w2v.x; acc[0][9]  += zb.x*w2v.y;
        acc[0][10] += zb.x*w2v.z; acc[0][11] += zb.x*w2v.w;
        acc[0][12] += zb.x*w3.x; acc[0][13] += zb.x*w3.y;
        acc[0][14] += zb.x*w3.z; acc[0][15] += zb.x*w3.w;
        acc[1][0]  += za.y*w0.x; acc[1][1]  += za.y*w0.y;
        acc[1][2]  += za.y*w0.z; acc[1][3]  += za.y*w0.w;
        acc[1][4]  += za.y*w1.x; acc[1][5]  += za.y*w1.y;
        acc[1][6]  += za.y*w1.z; acc[1][7]  += za.y*w1.w;
        acc[1][8]  += zb.y*w2v.x; acc[1][9]  += zb.y*w2v.y;
        acc[1][10] += zb.y*w2v.z; acc[1][11] += zb.y*w2v.w;
        acc[1][12] += zb.y*w3.x; acc[1][13] += zb.y*w3.y;
        acc[1][14] += zb.y*w3.z; acc[1][15] += zb.y*w3.w;
    }

#pragma unroll
    for (int i = 0; i < 2; ++i) {
        const int t = t0 + m*2 + i;
        if (t < T2) {
#pragma unroll
            for (int k = 0; k < 4; ++k) {
                float* __restrict__ xp = (k < 2) ? xh0 : xh1;
                const int jl = jb + 64 * (k & 1);
                float4 o = make_float4(acc[i][4*k+0], acc[i][4*k+1],
                                       acc[i][4*k+2], acc[i][4*k+3]);
                *reinterpret_cast<float4*>(&xp[(size_t)t*128 + jl]) = o;
            }
        }
    }
}

// ---------------------------------------------------------------- launch ---
extern "C" void kernel_launch(void* const* d_in, const int* in_sizes, int n_in,
                              void* d_out, int out_size, void* d_ws, size_t ws_size,
                              hipStream_t stream)
{
    const float* x0      = (const float*)d_in[0];
    const float* x1      = (const float*)d_in[1];
    const float* W1      = (const float*)d_in[2];
    const float* b1      = (const float*)d_in[3];
    const float* V2      = (const float*)d_in[4];
    const float* b2      = (const float*)d_in[5];
    const float* mus     = (const float*)d_in[6];
    const float* sigmas  = (const float*)d_in[7];
    const float* scaling = (const float*)d_in[8];
    float* out = (float*)d_out;
    float* ws  = (float*)d_ws;

    const int T  = in_sizes[0] / 128;
    const int T2 = T - 80;

    float* zd0 = out;
    float* zd1 = out + (size_t)T2 * NH;
    float* xh0 = out + (size_t)2 * T2 * NH;
    float* xh1 = xh0 + (size_t)T2 * 128;

    // intermediates inside not-yet-written output regions (dead before overwrite):
    // z0,z1 (2*T*32 = 16.8M floats) fit in xh0 region (T2*128 = 33.5M floats);
    // consumed by encdec before readout writes xh0. z is never materialized.
    float* z0 = xh0;
    float* z1 = xh0 + (size_t)T * NH;

    setup_kernel<<<1, 256, 0, stream>>>(V2, mus, sigmas, scaling, ws);
    proj_kernel<<<T / 128, 256, 0, stream>>>(x0, x1, W1, z0, z1, T);
    encdec_kernel<<<(T2 + ED_BT - 1) / ED_BT, 512, 0, stream>>>(
        z0, z1, b1, ws, zd0, zd1, T, T2);
    readout_kernel<<<(T2 + 63) / 64, 512, 0, stream>>>(zd0, zd1, ws + WS_W2T, b2,
                                                       xh0, xh1, T2);
}

// Round 8
// 647.456 us; speedup vs baseline: 2.8583x; 1.0172x over previous
//
#include <hip/hip_runtime.h>
#include <math.h>

// Problem constants
#define FL 41            // filter length
#define NH 32            // hidden channels
// ws float offsets
#define WS_E0  0         // encode filter region0 [32][41]
#define WS_E1  1312
#define WS_G0  2624      // decode filter region0
#define WS_G1  3936
#define WS_W2T 5248      // normalized W2^T [32][256]

// ---------------------------------------------------------------- setup ----
__global__ __launch_bounds__(256) void setup_kernel(
    const float* __restrict__ V2, const float* __restrict__ mus,
    const float* __restrict__ sigmas, const float* __restrict__ scaling,
    float* __restrict__ ws)
{
    const int tid = threadIdx.x;
    __shared__ float nrm[NH];
    // parallel column-norm: 8 threads per h, each sums 32 strided rows
    {
        const int h = tid >> 3;          // 0..31
        const int s = tid & 7;           // 0..7
        float p = 0.f;
        for (int jj = 0; jj < 32; ++jj) {
            const float v = V2[(s + jj*8)*NH + h];
            p += v*v;
        }
        p += __shfl_xor(p, 1, 8);
        p += __shfl_xor(p, 2, 8);
        p += __shfl_xor(p, 4, 8);
        if (s == 0) nrm[h] = sqrtf(p);
    }
    __syncthreads();
    // W2T[h][j] = V2[j][h] / nrm[h]
    for (int idx = tid; idx < NH*256; idx += 256) {
        int h = idx >> 8, j = idx & 255;
        ws[WS_W2T + idx] = V2[j*NH + h] / nrm[h];
    }
    // filters: order e0,e1,g0,g1 ; each [32][41]
    for (int idx = tid; idx < 4*NH*FL; idx += 256) {
        int bank = idx / (NH*FL);
        int rem  = idx - bank*(NH*FL);
        int h = rem / FL, l = rem - h*FL;
        int r = bank & 1;
        float mu = mus[r*NH + h];
        float sg = fmaxf(sigmas[r*NH + h], 1.0f);  // clamp(min=1)
        float C  = scaling[r*NH + h];
        float m  = (bank < 2) ? -mu : mu;          // encode uses flipped mu
        float x  = (float)(l - 21);                // XVALS = -21..19
        float dd = (x - m) / sg;
        ws[idx] = C * expf(-0.5f * dd * dd);
    }
}

// ----------------------------------------------------------------- proj ----
// z0 = x0 @ W1[:, :128]^T ; z1 = x1 @ W1[:, 128:]^T      ([T,32] each)
// (UNCHANGED for differential attribution)
__global__ __launch_bounds__(256) void proj_kernel(
    const float* __restrict__ x0, const float* __restrict__ x1,
    const float* __restrict__ W1,
    float* __restrict__ z0, float* __restrict__ z1, int T)
{
    __shared__ float xT[2][32][132];  // [region][c][s pad]
    __shared__ float wT[2][32][36];   // [region][c][h pad]
    const int tid  = threadIdx.x;
    const int row0 = blockIdx.x * 128;

    const int reg = tid >> 7;          // 0..1
    const int h0  = ((tid >> 5) & 3) * 8;
    const int m   = tid & 31;          // s0 = 4*m

    float acc[4][8];
#pragma unroll
    for (int i = 0; i < 4; ++i)
#pragma unroll
        for (int j = 0; j < 8; ++j) acc[i][j] = 0.f;

    for (int kc = 0; kc < 4; ++kc) {
        const int c0 = kc * 32;
#pragma unroll
        for (int r = 0; r < 2; ++r) {
            const float* __restrict__ xp = r ? x1 : x0;
#pragma unroll
            for (int p = 0; p < 4; ++p) {
                const int row = p*32 + (tid >> 3);
                const int c   = (tid & 7) * 4;
                const float4 v = *reinterpret_cast<const float4*>(
                    &xp[(size_t)(row0 + row)*128 + c0 + c]);
                xT[r][c+0][row] = v.x; xT[r][c+1][row] = v.y;
                xT[r][c+2][row] = v.z; xT[r][c+3][row] = v.w;
            }
        }
        {
            const int h = tid >> 3;
            const int c = (tid & 7) * 4;
            const float4 a = *reinterpret_cast<const float4*>(&W1[h*256 + c0 + c]);
            wT[0][c+0][h] = a.x; wT[0][c+1][h] = a.y;
            wT[0][c+2][h] = a.z; wT[0][c+3][h] = a.w;
            const float4 b = *reinterpret_cast<const float4*>(&W1[h*256 + 128 + c0 + c]);
            wT[1][c+0][h] = b.x; wT[1][c+1][h] = b.y;
            wT[1][c+2][h] = b.z; wT[1][c+3][h] = b.w;
        }
        __syncthreads();
#pragma unroll
        for (int c = 0; c < 32; ++c) {
            const float4 xv = *reinterpret_cast<const float4*>(&xT[reg][c][m*4]);
            const float4 wa = *reinterpret_cast<const float4*>(&wT[reg][c][h0]);
            const float4 wb = *reinterpret_cast<const float4*>(&wT[reg][c][h0+4]);
            const float xs[4] = {xv.x, xv.y, xv.z, xv.w};
            const float wv[8] = {wa.x, wa.y, wa.z, wa.w, wb.x, wb.y, wb.z, wb.w};
#pragma unroll
            for (int i = 0; i < 4; ++i)
#pragma unroll
                for (int j = 0; j < 8; ++j) acc[i][j] += xs[i] * wv[j];
        }
        __syncthreads();
    }
    float* __restrict__ zp = reg ? z1 : z0;
#pragma unroll
    for (int i = 0; i < 4; ++i) {
        const size_t r = (size_t)(row0 + m*4 + i) * NH + h0;
        float4 o0 = make_float4(acc[i][0], acc[i][1], acc[i][2], acc[i][3]);
        float4 o1 = make_float4(acc[i][4], acc[i][5], acc[i][6], acc[i][7]);
        *reinterpret_cast<float4*>(&zp[r])   = o0;
        *reinterpret_cast<float4*>(&zp[r+4]) = o1;
    }
}

// --------------------------------------------------------------- encdec ----
// Fused encode+decode: z never touches HBM. (UNCHANGED from round 5)
#define ED_BT 128
#define ED_RS 216   // staged z0/z1 rows (176 + 40)
#define ED_ZR 176   // z tile rows (16*11)
__global__ __launch_bounds__(512) void encdec_kernel(
    const float* __restrict__ z0, const float* __restrict__ z1,
    const float* __restrict__ b1, const float* __restrict__ ws,
    float* __restrict__ zd0, float* __restrict__ zd1,
    int T, int T2)
{
    __shared__ float s0[ED_RS][NH];
    __shared__ float s1[ED_RS][NH];
    __shared__ float zt[ED_ZR][NH];
    const int tid = threadIdx.x;
    const int t0  = blockIdx.x * ED_BT;

    // stage z0,z1 rows [t0, t0+216), coalesced float4
    for (int idx = tid; idx < ED_RS*NH/4; idx += 512) {
        const int f = idx*4, row = f >> 5, col = f & 31;
        const int gr = t0 + row;
        float4 a = make_float4(0.f,0.f,0.f,0.f);
        float4 b = make_float4(0.f,0.f,0.f,0.f);
        if (gr < T) {
            a = *reinterpret_cast<const float4*>(&z0[(size_t)gr*NH + col]);
            b = *reinterpret_cast<const float4*>(&z1[(size_t)gr*NH + col]);
        }
        *reinterpret_cast<float4*>(&s0[row][col]) = a;
        *reinterpret_cast<float4*>(&s1[row][col]) = b;
    }
    __syncthreads();

    const int h = tid & 31;
    // ---- encode phase: 16 groups x 11 z-rows
    {
        const int g  = tid >> 5;        // 0..15
        const int tb = g * 11;
        float acc[11];
        const float bb = b1[h];
#pragma unroll
        for (int i = 0; i < 11; ++i) acc[i] = bb;
        float fr[FL];
#pragma unroll
        for (int l = 0; l < FL; ++l) fr[l] = ws[WS_E0 + h*FL + l];
#pragma unroll
        for (int s = 0; s < 51; ++s) {
            const float a0 = s0[tb + s][h];
#pragma unroll
            for (int i = 0; i < 11; ++i) {
                const int l = s - i;
                if (l >= 0 && l < FL) acc[i] += a0 * fr[l];
            }
        }
#pragma unroll
        for (int l = 0; l < FL; ++l) fr[l] = ws[WS_E1 + h*FL + l];
#pragma unroll
        for (int s = 0; s < 51; ++s) {
            const float a1 = s1[tb + s][h];
#pragma unroll
            for (int i = 0; i < 11; ++i) {
                const int l = s - i;
                if (l >= 0 && l < FL) acc[i] += a1 * fr[l];
            }
        }
#pragma unroll
        for (int i = 0; i < 11; ++i) zt[tb + i][h] = acc[i];
    }
    __syncthreads();

    // ---- decode phase: 2 regions x 8 groups x 16 zd-rows
    {
        const int rr = (tid >> 5) & 1;
        const int g  = tid >> 6;        // 0..7
        const int tb = g * 16;
        float fr[FL];
        const float* __restrict__ fb = ws + (rr ? WS_G1 : WS_G0);
#pragma unroll
        for (int l = 0; l < FL; ++l) fr[l] = fb[h*FL + l];
        float acc[16];
#pragma unroll
        for (int i = 0; i < 16; ++i) acc[i] = 0.f;
#pragma unroll
        for (int s = 0; s < 56; ++s) {
            const float a = zt[tb + s][h];
#pragma unroll
            for (int i = 0; i < 16; ++i) {
                const int l = s - i;
                if (l >= 0 && l < FL) acc[i] += a * fr[l];
            }
        }
        float* __restrict__ zd = rr ? zd1 : zd0;
#pragma unroll
        for (int i = 0; i < 16; ++i) {
            const int t = t0 + tb + i;
            if (t < T2) zd[(size_t)t*NH + h] = acc[i];
        }
    }
}

// -------------------------------------------------------------- readout ----
// xh0 = zd0 @ W2T[:, :128] + b2[:128] ; xh1 = zd1 @ W2T[:, 128:] + b2[128:]
// Coalesced-store mapping. Block 512 thr, BT=128 rows.
// Thread (j = (tid&31)*4, r = bit5, rw = tid>>6): 16 rows (rw*16+i), 4 cols.
//   Wave stores: lanes 0-31 -> xh_r row contiguous 512B, lanes 32-63 -> other
//   region same row -> 2 x 512B segments per store instruction.
//   w2[r][h][j]: lanes read 128 consecutive floats -> conflict-free.
//   sz[r][row][h]: wave-broadcast (2 addrs/instr, same bank, 2-way = free).
#define RO_BT 128
__global__ __launch_bounds__(512) void readout_kernel(
    const float* __restrict__ zd0, const float* __restrict__ zd1,
    const float* __restrict__ W2T, const float* __restrict__ b2,
    float* __restrict__ xh0, float* __restrict__ xh1, int T2)
{
    __shared__ float w2[2][NH][132];   // [region][h][j], 132 pad (16B-aligned rows)
    __shared__ float sz[2][RO_BT][NH]; // [region][row][h], untransposed
    const int tid = threadIdx.x;
    const int t0  = blockIdx.x * RO_BT;

    // stage W2T (L2-hot): 2048 float4s, split into region halves
    for (int idx = tid; idx < 2048; idx += 512) {
        const int h  = idx >> 6;           // 0..31
        const int jj = (idx & 63) * 4;     // 0..252
        const int r  = jj >> 7;
        const int j  = jj & 127;
        *reinterpret_cast<float4*>(&w2[r][h][j]) =
            *reinterpret_cast<const float4*>(&W2T[h*256 + jj]);
    }
    // stage zd: direct copy (no transpose), 2048 float4s
    for (int idx = tid; idx < 2048; idx += 512) {
        const int f   = idx * 4;           // 0..8188
        const int r   = f >> 12;           // / (128*32)
        const int rem = f & 4095;
        const int row = rem >> 5, col = rem & 31;
        const int t   = t0 + row;
        float4 v = make_float4(0.f, 0.f, 0.f, 0.f);
        if (t < T2) {
            const float* __restrict__ zp = r ? zd1 : zd0;
            v = *reinterpret_cast<const float4*>(&zp[(size_t)t*NH + col]);
        }
        *reinterpret_cast<float4*>(&sz[r][row][col]) = v;
    }
    __syncthreads();

    const int j  = (tid & 31) * 4;     // 0..124
    const int r  = (tid >> 5) & 1;     // region
    const int rw = tid >> 6;           // 0..7 row-group

    float acc[16][4];
    {
        const float4 bv = *reinterpret_cast<const float4*>(&b2[r*128 + j]);
#pragma unroll
        for (int i = 0; i < 16; ++i) {
            acc[i][0] = bv.x; acc[i][1] = bv.y;
            acc[i][2] = bv.z; acc[i][3] = bv.w;
        }
    }

#pragma unroll 4
    for (int h = 0; h < NH; ++h) {
        const float4 w = *reinterpret_cast<const float4*>(&w2[r][h][j]);
#pragma unroll
        for (int i = 0; i < 16; ++i) {
            const float zv = sz[r][rw*16 + i][h];
            acc[i][0] += zv * w.x;
            acc[i][1] += zv * w.y;
            acc[i][2] += zv * w.z;
            acc[i][3] += zv * w.w;
        }
    }

    float* __restrict__ xp = r ? xh1 : xh0;
#pragma unroll
    for (int i = 0; i < 16; ++i) {
        const int t = t0 + rw*16 + i;
        if (t < T2) {
            float4 o = make_float4(acc[i][0], acc[i][1], acc[i][2], acc[i][3]);
            *reinterpret_cast<float4*>(&xp[(size_t)t*128 + j]) = o;
        }
    }
}

// ---------------------------------------------------------------- launch ---
extern "C" void kernel_launch(void* const* d_in, const int* in_sizes, int n_in,
                              void* d_out, int out_size, void* d_ws, size_t ws_size,
                              hipStream_t stream)
{
    const float* x0      = (const float*)d_in[0];
    const float* x1      = (const float*)d_in[1];
    const float* W1      = (const float*)d_in[2];
    const float* b1      = (const float*)d_in[3];
    const float* V2      = (const float*)d_in[4];
    const float* b2      = (const float*)d_in[5];
    const float* mus     = (const float*)d_in[6];
    const float* sigmas  = (const float*)d_in[7];
    const float* scaling = (const float*)d_in[8];
    float* out = (float*)d_out;
    float* ws  = (float*)d_ws;

    const int T  = in_sizes[0] / 128;
    const int T2 = T - 80;

    float* zd0 = out;
    float* zd1 = out + (size_t)T2 * NH;
    float* xh0 = out + (size_t)2 * T2 * NH;
    float* xh1 = xh0 + (size_t)T2 * 128;

    // intermediates inside not-yet-written output regions (dead before overwrite):
    // z0,z1 (2*T*32 = 16.8M floats) fit in xh0 region (T2*128 = 33.5M floats);
    // consumed by encdec before readout writes xh0. z is never materialized.
    float* z0 = xh0;
    float* z1 = xh0 + (size_t)T * NH;

    setup_kernel<<<1, 256, 0, stream>>>(V2, mus, sigmas, scaling, ws);
    proj_kernel<<<T / 128, 256, 0, stream>>>(x0, x1, W1, z0, z1, T);
    encdec_kernel<<<(T2 + ED_BT - 1) / ED_BT, 512, 0, stream>>>(
        z0, z1, b1, ws, zd0, zd1, T, T2);
    readout_kernel<<<(T2 + RO_BT - 1) / RO_BT, 512, 0, stream>>>(
        zd0, zd1, ws + WS_W2T, b2, xh0, xh1, T2);
}